// Round 11
// baseline (86.342 us; speedup 1.0000x reference)
//
#include <hip/hip_runtime.h>

#define Q 4096
#define L 8192
#define NCHUNK 4
#define CROWS (L / NCHUNK)        // 2048 rows per chunk
#define WROWS 16                  // rows per wsum block
#define NPB (L / WROWS)           // 512 partial rows total
#define WCB 4                     // col-chunks per wsum row-group (1024 f4 cols)

// ---------------------------------------------------------------------------
// K1 (per chunk): score[l] = ctx[l].q — wave-per-row, no LDS, no barriers.
// ---------------------------------------------------------------------------
__global__ __launch_bounds__(256) void score_kernel(
    const float* __restrict__ ctx, const float* __restrict__ qvec,
    float* __restrict__ score, int r0base)
{
    const int lane = threadIdx.x & 63;
    const int w    = r0base + blockIdx.x * 4 + (threadIdx.x >> 6);
    const float4* __restrict__ row = (const float4*)(ctx + (size_t)w * Q);
    const float4* __restrict__ qv  = (const float4*)qvec;

    float a0 = 0.f, a1 = 0.f, a2 = 0.f, a3 = 0.f;
    #pragma unroll
    for (int c = 0; c < 16; c += 4) {
        float4 x0 = row[(c + 0) * 64 + lane], y0 = qv[(c + 0) * 64 + lane];
        float4 x1 = row[(c + 1) * 64 + lane], y1 = qv[(c + 1) * 64 + lane];
        float4 x2 = row[(c + 2) * 64 + lane], y2 = qv[(c + 2) * 64 + lane];
        float4 x3 = row[(c + 3) * 64 + lane], y3 = qv[(c + 3) * 64 + lane];
        a0 = fmaf(x0.x, y0.x, a0); a0 = fmaf(x0.y, y0.y, a0);
        a0 = fmaf(x0.z, y0.z, a0); a0 = fmaf(x0.w, y0.w, a0);
        a1 = fmaf(x1.x, y1.x, a1); a1 = fmaf(x1.y, y1.y, a1);
        a1 = fmaf(x1.z, y1.z, a1); a1 = fmaf(x1.w, y1.w, a1);
        a2 = fmaf(x2.x, y2.x, a2); a2 = fmaf(x2.y, y2.y, a2);
        a2 = fmaf(x2.z, y2.z, a2); a2 = fmaf(x2.w, y2.w, a2);
        a3 = fmaf(x3.x, y3.x, a3); a3 = fmaf(x3.y, y3.y, a3);
        a3 = fmaf(x3.z, y3.z, a3); a3 = fmaf(x3.w, y3.w, a3);
    }
    float d = (a0 + a1) + (a2 + a3);
    #pragma unroll
    for (int off = 32; off > 0; off >>= 1) d += __shfl_down(d, off, 64);
    if (lane == 0) score[w] = d;
}

// ---------------------------------------------------------------------------
// K2 (per chunk): unnormalized weighted sum over 16-row groups, re-reading
//   rows from L3 (read by score_kernel at most ~32 MB of traffic ago).
//   Block = (row-group rg of 16 rows) x (col-chunk cc of 256 f4 cols).
//   Local max m_b over the 16 scores; weights exp(s - m_b); writes
//   partial[pb][col] and (m_arr[pb], Z_arr[pb]).  Two cheap barriers total.
// ---------------------------------------------------------------------------
__global__ __launch_bounds__(256) void wsum_kernel(
    const float* __restrict__ ctx, const float* __restrict__ score,
    float* __restrict__ partial, float* __restrict__ m_arr,
    float* __restrict__ Z_arr, int r0base)
{
    __shared__ float sc_s[WROWS];
    __shared__ float w_s[WROWS];
    const int cc  = blockIdx.x & (WCB - 1);
    const int rg  = blockIdx.x / WCB;            // row-group within chunk
    const int r0  = r0base + rg * WROWS;
    const int pb  = r0 / WROWS;                  // global partial row id
    const int tid = threadIdx.x;

    if (tid < WROWS) sc_s[tid] = score[r0 + tid];
    __syncthreads();
    float m = sc_s[0];
    #pragma unroll
    for (int r = 1; r < WROWS; ++r) m = fmaxf(m, sc_s[r]);
    if (tid < WROWS) w_s[tid] = __expf(sc_s[tid] - m);
    __syncthreads();

    const int col = cc * 256 + tid;              // float4 column
    const float4* __restrict__ cb = (const float4*)ctx;
    float4 acc = make_float4(0.f, 0.f, 0.f, 0.f);
    #pragma unroll
    for (int r = 0; r < WROWS; ++r) {
        const float a = w_s[r];
        float4 v = cb[(size_t)(r0 + r) * (Q / 4) + col];
        acc.x = fmaf(a, v.x, acc.x);
        acc.y = fmaf(a, v.y, acc.y);
        acc.z = fmaf(a, v.z, acc.z);
        acc.w = fmaf(a, v.w, acc.w);
    }
    ((float4*)partial)[(size_t)pb * (Q / 4) + col] = acc;

    if (cc == 0 && tid == 0) {
        float Z = 0.f;
        #pragma unroll
        for (int r = 0; r < WROWS; ++r) Z += w_s[r];
        m_arr[pb] = m;
        Z_arr[pb] = Z;
    }
}

// ---------------------------------------------------------------------------
// K3: merge NPB partials: s_t[j] = (1/Z_tot) * sum_b exp(m_b - M) p_b[j].
//   64 blocks x 16 f4-cols; 16 b-groups sweep NPB.
// ---------------------------------------------------------------------------
__global__ __launch_bounds__(256) void merge_kernel(
    const float* __restrict__ partial, const float* __restrict__ m_arr,
    const float* __restrict__ Z_arr, float* __restrict__ s_t)
{
    __shared__ float wc[NPB];          // 2 KB
    __shared__ float red[4];
    __shared__ float4 sacc[16][16];    // 4 KB
    const int tid  = threadIdx.x;
    const int lane = tid & 63;
    const int wid  = tid >> 6;

    // global max M over NPB=512 (2 per thread)
    float mv = fmaxf(m_arr[tid], m_arr[tid + 256]);
    #pragma unroll
    for (int off = 32; off > 0; off >>= 1) mv = fmaxf(mv, __shfl_down(mv, off, 64));
    if (lane == 0) red[wid] = mv;
    __syncthreads();
    const float M = fmaxf(fmaxf(red[0], red[1]), fmaxf(red[2], red[3]));
    __syncthreads();

    // weights + Z_tot
    const float w0 = __expf(m_arr[tid] - M);
    const float w1 = __expf(m_arr[tid + 256] - M);
    wc[tid] = w0; wc[tid + 256] = w1;
    float zv = fmaf(w0, Z_arr[tid], w1 * Z_arr[tid + 256]);
    #pragma unroll
    for (int off = 32; off > 0; off >>= 1) zv += __shfl_down(zv, off, 64);
    if (lane == 0) red[wid] = zv;
    __syncthreads();
    const float invZ = 1.f / (red[0] + red[1] + red[2] + red[3]);

    // weighted column sums
    const int cidx = tid & 15;
    const int g    = tid >> 4;                 // 16 b-groups
    const int c4   = blockIdx.x * 16 + cidx;
    const float4* __restrict__ p = (const float4*)partial;
    float4 acc = make_float4(0.f, 0.f, 0.f, 0.f);
    for (int b = g; b < NPB; b += 16) {
        const float w = wc[b];
        float4 v = p[(size_t)b * (Q / 4) + c4];
        acc.x = fmaf(w, v.x, acc.x); acc.y = fmaf(w, v.y, acc.y);
        acc.z = fmaf(w, v.z, acc.z); acc.w = fmaf(w, v.w, acc.w);
    }
    sacc[g][cidx] = acc;
    __syncthreads();
    if (g == 0) {
        float4 t = sacc[0][cidx];
        #pragma unroll
        for (int gg = 1; gg < 16; ++gg) {
            float4 u = sacc[gg][cidx];
            t.x += u.x; t.y += u.y; t.z += u.z; t.w += u.w;
        }
        t.x *= invZ; t.y *= invZ; t.z *= invZ; t.w *= invZ;
        ((float4*)s_t)[c4] = t;
    }
}

// ---------------------------------------------------------------------------
// K4: out[i] = Kw[i,0:Q].q + Kw[i,Q:2Q].s_t — wave-per-row over the full
//     32 KB Kw row, contiguous stream, no LDS, no barriers.
// ---------------------------------------------------------------------------
__global__ __launch_bounds__(256) void out_kernel(
    const float* __restrict__ Kw, const float* __restrict__ qvec,
    const float* __restrict__ s_t, float* __restrict__ out)
{
    const int lane = threadIdx.x & 63;
    const int i    = blockIdx.x * 4 + (threadIdx.x >> 6);   // 0..4095
    const float4* __restrict__ row = (const float4*)(Kw + (size_t)i * (2 * Q));
    const float4* __restrict__ qv  = (const float4*)qvec;
    const float4* __restrict__ sv  = (const float4*)s_t;

    float a0 = 0.f, a1 = 0.f, a2 = 0.f, a3 = 0.f;
    #pragma unroll
    for (int c = 0; c < 16; c += 4) {
        float4 x0 = row[(c + 0) * 64 + lane], y0 = qv[(c + 0) * 64 + lane];
        float4 x1 = row[(c + 1) * 64 + lane], y1 = qv[(c + 1) * 64 + lane];
        float4 x2 = row[(c + 2) * 64 + lane], y2 = qv[(c + 2) * 64 + lane];
        float4 x3 = row[(c + 3) * 64 + lane], y3 = qv[(c + 3) * 64 + lane];
        a0 = fmaf(x0.x, y0.x, a0); a0 = fmaf(x0.y, y0.y, a0);
        a0 = fmaf(x0.z, y0.z, a0); a0 = fmaf(x0.w, y0.w, a0);
        a1 = fmaf(x1.x, y1.x, a1); a1 = fmaf(x1.y, y1.y, a1);
        a1 = fmaf(x1.z, y1.z, a1); a1 = fmaf(x1.w, y1.w, a1);
        a2 = fmaf(x2.x, y2.x, a2); a2 = fmaf(x2.y, y2.y, a2);
        a2 = fmaf(x2.z, y2.z, a2); a2 = fmaf(x2.w, y2.w, a2);
        a3 = fmaf(x3.x, y3.x, a3); a3 = fmaf(x3.y, y3.y, a3);
        a3 = fmaf(x3.z, y3.z, a3); a3 = fmaf(x3.w, y3.w, a3);
    }
    #pragma unroll
    for (int c = 0; c < 16; c += 4) {
        float4 x0 = row[(16 + c + 0) * 64 + lane], y0 = sv[(c + 0) * 64 + lane];
        float4 x1 = row[(16 + c + 1) * 64 + lane], y1 = sv[(c + 1) * 64 + lane];
        float4 x2 = row[(16 + c + 2) * 64 + lane], y2 = sv[(c + 2) * 64 + lane];
        float4 x3 = row[(16 + c + 3) * 64 + lane], y3 = sv[(c + 3) * 64 + lane];
        a0 = fmaf(x0.x, y0.x, a0); a0 = fmaf(x0.y, y0.y, a0);
        a0 = fmaf(x0.z, y0.z, a0); a0 = fmaf(x0.w, y0.w, a0);
        a1 = fmaf(x1.x, y1.x, a1); a1 = fmaf(x1.y, y1.y, a1);
        a1 = fmaf(x1.z, y1.z, a1); a1 = fmaf(x1.w, y1.w, a1);
        a2 = fmaf(x2.x, y2.x, a2); a2 = fmaf(x2.y, y2.y, a2);
        a2 = fmaf(x2.z, y2.z, a2); a2 = fmaf(x2.w, y2.w, a2);
        a3 = fmaf(x3.x, y3.x, a3); a3 = fmaf(x3.y, y3.y, a3);
        a3 = fmaf(x3.z, y3.z, a3); a3 = fmaf(x3.w, y3.w, a3);
    }
    float d = (a0 + a1) + (a2 + a3);
    #pragma unroll
    for (int off = 32; off > 0; off >>= 1) d += __shfl_down(d, off, 64);
    if (lane == 0) out[i] = d;
}

// ---------------------------------------------------------------------------
extern "C" void kernel_launch(void* const* d_in, const int* in_sizes, int n_in,
                              void* d_out, int out_size, void* d_ws, size_t ws_size,
                              hipStream_t stream)
{
    const float* query = (const float*)d_in[0];   // [Q]
    const float* ctx   = (const float*)d_in[1];   // [L, Q]
    const float* Kw    = (const float*)d_in[2];   // [Q, 2Q]
    float* out = (float*)d_out;                   // [Q]

    // workspace layout (floats)
    float* ws      = (float*)d_ws;
    float* score   = ws;                          // L        = 8192
    float* m_arr   = ws + L;                      // NPB      = 512
    float* Z_arr   = ws + L + NPB;                // NPB      = 512
    float* s_t     = ws + L + 2 * NPB;            // Q        = 4096
    float* partial = ws + L + 2 * NPB + Q;        // NPB * Q  = 8 MiB

    for (int c = 0; c < NCHUNK; ++c) {
        const int r0 = c * CROWS;
        score_kernel<<<CROWS / 4, 256, 0, stream>>>(ctx, query, score, r0);
        wsum_kernel<<<(CROWS / WROWS) * WCB, 256, 0, stream>>>(
            ctx, score, partial, m_arr, Z_arr, r0);
    }
    merge_kernel<<<Q / 4 / 16, 256, 0, stream>>>(partial, m_arr, Z_arr, s_t);
    out_kernel<<<Q / 4, 256, 0, stream>>>(Kw, query, s_t, out);
}